// Round 2
// baseline (133.500 us; speedup 1.0000x reference)
//
#include <hip/hip_runtime.h>
#include <cstdint>
#include <cstddef>

#define LRALPHA 0.2f

typedef _Float16 half8 __attribute__((ext_vector_type(8)));
typedef float f32x4 __attribute__((ext_vector_type(4)));

// ---------------------------------------------------------------------------
// Kernel 1: Wh = h @ W  (8192x512 @ 512x64), writes:
//   whT  : f16 [64][8192]   (transposed, feeds MFMA B-fragments directly)
//   wh1  : f32 [8192]       (Wh @ a[:64])
//   wh2  : f32 [8192]       (Wh @ a[64:])
// ---------------------------------------------------------------------------
__global__ __launch_bounds__(256) void k1_wh(
    const float* __restrict__ h, const float* __restrict__ W, const float* __restrict__ a,
    _Float16* __restrict__ whT, float* __restrict__ wh1, float* __restrict__ wh2)
{
  __shared__ __align__(16) float h_lds[32][34];   // [k][row]
  __shared__ __align__(16) float w_lds[32][64];   // [k][col]
  __shared__ __align__(16) _Float16 whT_l[64][32];

  const int t = threadIdx.x;
  const int tx = t & 15, ty = t >> 4;
  const int i0 = blockIdx.x * 32;

  const int hrow = t >> 3, hk4 = (t & 7) * 4;
  const int wk = t >> 3, wc = (t & 7) * 8;

  float acc00 = 0, acc01 = 0, acc02 = 0, acc03 = 0;
  float acc10 = 0, acc11 = 0, acc12 = 0, acc13 = 0;

  float4 hv  = *reinterpret_cast<const float4*>(&h[(size_t)(i0 + hrow) * 512 + hk4]);
  float4 wv0 = *reinterpret_cast<const float4*>(&W[(size_t)wk * 64 + wc]);
  float4 wv1 = *reinterpret_cast<const float4*>(&W[(size_t)wk * 64 + wc + 4]);

  for (int k0 = 0; k0 < 512; k0 += 32) {
    h_lds[hk4 + 0][hrow] = hv.x;
    h_lds[hk4 + 1][hrow] = hv.y;
    h_lds[hk4 + 2][hrow] = hv.z;
    h_lds[hk4 + 3][hrow] = hv.w;
    *reinterpret_cast<float4*>(&w_lds[wk][wc])     = wv0;
    *reinterpret_cast<float4*>(&w_lds[wk][wc + 4]) = wv1;
    __syncthreads();
    if (k0 + 32 < 512) {
      hv  = *reinterpret_cast<const float4*>(&h[(size_t)(i0 + hrow) * 512 + k0 + 32 + hk4]);
      wv0 = *reinterpret_cast<const float4*>(&W[(size_t)(k0 + 32 + wk) * 64 + wc]);
      wv1 = *reinterpret_cast<const float4*>(&W[(size_t)(k0 + 32 + wk) * 64 + wc + 4]);
    }
#pragma unroll
    for (int kk = 0; kk < 32; ++kk) {
      float2 av = *reinterpret_cast<const float2*>(&h_lds[kk][ty * 2]);
      float4 bv = *reinterpret_cast<const float4*>(&w_lds[kk][tx * 4]);
      acc00 += av.x * bv.x; acc01 += av.x * bv.y; acc02 += av.x * bv.z; acc03 += av.x * bv.w;
      acc10 += av.y * bv.x; acc11 += av.y * bv.y; acc12 += av.y * bv.z; acc13 += av.y * bv.w;
    }
    __syncthreads();
  }

  const float a10 = a[tx * 4 + 0], a11 = a[tx * 4 + 1], a12 = a[tx * 4 + 2], a13 = a[tx * 4 + 3];
  const float a20 = a[64 + tx * 4 + 0], a21 = a[64 + tx * 4 + 1], a22 = a[64 + tx * 4 + 2], a23 = a[64 + tx * 4 + 3];
  float s1_0 = acc00 * a10 + acc01 * a11 + acc02 * a12 + acc03 * a13;
  float s1_1 = acc10 * a10 + acc11 * a11 + acc12 * a12 + acc13 * a13;
  float s2_0 = acc00 * a20 + acc01 * a21 + acc02 * a22 + acc03 * a23;
  float s2_1 = acc10 * a20 + acc11 * a21 + acc12 * a22 + acc13 * a23;
#pragma unroll
  for (int m = 1; m < 16; m <<= 1) {
    s1_0 += __shfl_xor(s1_0, m); s1_1 += __shfl_xor(s1_1, m);
    s2_0 += __shfl_xor(s2_0, m); s2_1 += __shfl_xor(s2_1, m);
  }
  if (tx == 0) {
    wh1[i0 + ty * 2 + 0] = s1_0; wh1[i0 + ty * 2 + 1] = s1_1;
    wh2[i0 + ty * 2 + 0] = s2_0; wh2[i0 + ty * 2 + 1] = s2_1;
  }

  whT_l[tx * 4 + 0][ty * 2 + 0] = (_Float16)acc00;
  whT_l[tx * 4 + 1][ty * 2 + 0] = (_Float16)acc01;
  whT_l[tx * 4 + 2][ty * 2 + 0] = (_Float16)acc02;
  whT_l[tx * 4 + 3][ty * 2 + 0] = (_Float16)acc03;
  whT_l[tx * 4 + 0][ty * 2 + 1] = (_Float16)acc10;
  whT_l[tx * 4 + 1][ty * 2 + 1] = (_Float16)acc11;
  whT_l[tx * 4 + 2][ty * 2 + 1] = (_Float16)acc12;
  whT_l[tx * 4 + 3][ty * 2 + 1] = (_Float16)acc13;
  __syncthreads();
  {
    const int c = t >> 2, r8 = (t & 3) * 8;
    half8 v = *reinterpret_cast<const half8*>(&whT_l[c][r8]);
    *reinterpret_cast<half8*>(&whT[(size_t)c * 8192 + i0 + r8]) = v;
  }
}

// ---------------------------------------------------------------------------
// Kernel 1b: G = max(wh2)
// ---------------------------------------------------------------------------
__global__ __launch_bounds__(256) void k1b_max(const float* __restrict__ wh2,
                                               float* __restrict__ G)
{
  const int t = threadIdx.x;
  float m = -1e30f;
  for (int i = t; i < 8192; i += 256) m = fmaxf(m, wh2[i]);
#pragma unroll
  for (int mask = 32; mask >= 1; mask >>= 1) m = fmaxf(m, __shfl_xor(m, mask));
  __shared__ float wm[4];
  if ((t & 63) == 0) wm[t >> 6] = m;
  __syncthreads();
  if (t == 0) G[0] = fmaxf(fmaxf(wm[0], wm[1]), fmaxf(wm[2], wm[3]));
}

// ---------------------------------------------------------------------------
// Kernel 2 (v2): barrier-free masked-softmax + PV.
// 512 blocks x 256 thr (4 waves). Block = 16 rows; wave w owns j-range
// [w*2048, (w+1)*2048). Each lane computes the P-values of its OWN MFMA
// A-fragment (row = lane&15, k = (lane>>4)*8+e) -> no LDS, no barriers in
// the main loop. Depth-2 register prefetch keeps ~32KB/CU adj in flight.
// Split-K combine: one LDS pass + single barrier at the end.
// ---------------------------------------------------------------------------
__global__ __launch_bounds__(256) void k2_attn(
    const int* __restrict__ adj, const _Float16* __restrict__ whT,
    const float* __restrict__ wh1, const float* __restrict__ wh2,
    const float* __restrict__ Gp, float* __restrict__ out)
{
  __shared__ __align__(16) float Osm[4][16][64];  // 16 KB split-K partials
  __shared__ float Dsm[4][16];

  const int t = threadIdx.x;
  const int lane = t & 63;
  const int w = t >> 6;            // wave id = K-split slice
  const int c = lane & 15;         // A-row / B-col / C-col index
  const int ks = lane >> 4;        // k-subgroup 0..3
  const int i0 = blockIdx.x * 16;

  const float Gv = Gp[0];
  const float w1r = wh1[i0 + c];
  const float mx = w1r + Gv;
  const float mh = fmaxf(mx, LRALPHA * mx);   // >= all scores of row c (lrelu monotone)

  const int*      adjp = adj + (size_t)(i0 + c) * 8192 + w * 2048 + ks * 8;
  const float*    wh2p = wh2 + w * 2048 + ks * 8;
  const _Float16* bp0  = whT + (size_t)c * 8192 + w * 2048 + ks * 8;
  const _Float16* bp1  = bp0 + (size_t)16 * 8192;
  const _Float16* bp2  = bp0 + (size_t)32 * 8192;
  const _Float16* bp3  = bp0 + (size_t)48 * 8192;

  f32x4 acc0 = {0.f,0.f,0.f,0.f}, acc1 = {0.f,0.f,0.f,0.f};
  f32x4 acc2 = {0.f,0.f,0.f,0.f}, acc3 = {0.f,0.f,0.f,0.f};
  float ps = 0.f;

  int4 Aa0, Aa1, Ba0, Ba1;
  float4 Aw0, Aw1, Bw0, Bw1;
  half8 Ab0, Ab1, Ab2, Ab3, Bb0, Bb1, Bb2, Bb3;

#define LOADSET(P, CI) do { const int jj_ = (CI) * 32;                          \
    P##a0 = *reinterpret_cast<const int4*>(adjp + jj_);                         \
    P##a1 = *reinterpret_cast<const int4*>(adjp + jj_ + 4);                     \
    P##w0 = *reinterpret_cast<const float4*>(wh2p + jj_);                       \
    P##w1 = *reinterpret_cast<const float4*>(wh2p + jj_ + 4);                   \
    P##b0 = *reinterpret_cast<const half8*>(bp0 + jj_);                         \
    P##b1 = *reinterpret_cast<const half8*>(bp1 + jj_);                         \
    P##b2 = *reinterpret_cast<const half8*>(bp2 + jj_);                         \
    P##b3 = *reinterpret_cast<const half8*>(bp3 + jj_); } while (0)

#define BODY(P, NEXTCI) do {                                                    \
    const int4 ca0 = P##a0, ca1 = P##a1;                                        \
    const float4 cw0 = P##w0, cw1 = P##w1;                                      \
    const half8 cb0 = P##b0, cb1 = P##b1, cb2 = P##b2, cb3 = P##b3;             \
    if ((NEXTCI) < 64) LOADSET(P, NEXTCI);                                      \
    half8 af;                                                                   \
    { float s_ = w1r + cw0.x; s_ = fmaxf(s_, LRALPHA*s_);                       \
      float p_ = (ca0.x > 0) ? __expf(s_ - mh) : 0.f; ps += p_; af[0] = (_Float16)p_; } \
    { float s_ = w1r + cw0.y; s_ = fmaxf(s_, LRALPHA*s_);                       \
      float p_ = (ca0.y > 0) ? __expf(s_ - mh) : 0.f; ps += p_; af[1] = (_Float16)p_; } \
    { float s_ = w1r + cw0.z; s_ = fmaxf(s_, LRALPHA*s_);                       \
      float p_ = (ca0.z > 0) ? __expf(s_ - mh) : 0.f; ps += p_; af[2] = (_Float16)p_; } \
    { float s_ = w1r + cw0.w; s_ = fmaxf(s_, LRALPHA*s_);                       \
      float p_ = (ca0.w > 0) ? __expf(s_ - mh) : 0.f; ps += p_; af[3] = (_Float16)p_; } \
    { float s_ = w1r + cw1.x; s_ = fmaxf(s_, LRALPHA*s_);                       \
      float p_ = (ca1.x > 0) ? __expf(s_ - mh) : 0.f; ps += p_; af[4] = (_Float16)p_; } \
    { float s_ = w1r + cw1.y; s_ = fmaxf(s_, LRALPHA*s_);                       \
      float p_ = (ca1.y > 0) ? __expf(s_ - mh) : 0.f; ps += p_; af[5] = (_Float16)p_; } \
    { float s_ = w1r + cw1.z; s_ = fmaxf(s_, LRALPHA*s_);                       \
      float p_ = (ca1.z > 0) ? __expf(s_ - mh) : 0.f; ps += p_; af[6] = (_Float16)p_; } \
    { float s_ = w1r + cw1.w; s_ = fmaxf(s_, LRALPHA*s_);                       \
      float p_ = (ca1.w > 0) ? __expf(s_ - mh) : 0.f; ps += p_; af[7] = (_Float16)p_; } \
    acc0 = __builtin_amdgcn_mfma_f32_16x16x32_f16(af, cb0, acc0, 0, 0, 0);      \
    acc1 = __builtin_amdgcn_mfma_f32_16x16x32_f16(af, cb1, acc1, 0, 0, 0);      \
    acc2 = __builtin_amdgcn_mfma_f32_16x16x32_f16(af, cb2, acc2, 0, 0, 0);      \
    acc3 = __builtin_amdgcn_mfma_f32_16x16x32_f16(af, cb3, acc3, 0, 0, 0);      \
  } while (0)

  LOADSET(A, 0);
  LOADSET(B, 1);

  for (int ci = 0; ci < 64; ci += 2) {
    BODY(A, ci + 2);
    BODY(B, ci + 3);
  }
#undef BODY
#undef LOADSET

  // per-row denom partial: reduce across the 4 k-subgroups (lanes c, c+16, c+32, c+48)
  float r = ps;
  r += __shfl_xor(r, 16);
  r += __shfl_xor(r, 32);
  if (ks == 0) Dsm[w][c] = r;

#pragma unroll
  for (int q = 0; q < 4; ++q) {
    Osm[w][ks * 4 + q][ 0 + c] = acc0[q];
    Osm[w][ks * 4 + q][16 + c] = acc1[q];
    Osm[w][ks * 4 + q][32 + c] = acc2[q];
    Osm[w][ks * 4 + q][48 + c] = acc3[q];
  }
  __syncthreads();

  {
    const int row = t >> 4, c4 = (t & 15) * 4;
    float4 v0 = *reinterpret_cast<const float4*>(&Osm[0][row][c4]);
    float4 v1 = *reinterpret_cast<const float4*>(&Osm[1][row][c4]);
    float4 v2 = *reinterpret_cast<const float4*>(&Osm[2][row][c4]);
    float4 v3 = *reinterpret_cast<const float4*>(&Osm[3][row][c4]);
    const float d = Dsm[0][row] + Dsm[1][row] + Dsm[2][row] + Dsm[3][row];
    const float inv = 1.0f / d;
    float4 o;
    o.x = (v0.x + v1.x + v2.x + v3.x) * inv;
    o.y = (v0.y + v1.y + v2.y + v3.y) * inv;
    o.z = (v0.z + v1.z + v2.z + v3.z) * inv;
    o.w = (v0.w + v1.w + v2.w + v3.w) * inv;
    o.x = o.x > 0.f ? o.x : __expf(o.x) - 1.f;
    o.y = o.y > 0.f ? o.y : __expf(o.y) - 1.f;
    o.z = o.z > 0.f ? o.z : __expf(o.z) - 1.f;
    o.w = o.w > 0.f ? o.w : __expf(o.w) - 1.f;
    *reinterpret_cast<float4*>(&out[(size_t)(i0 + row) * 64 + c4]) = o;
  }
}

// ---------------------------------------------------------------------------
extern "C" void kernel_launch(void* const* d_in, const int* in_sizes, int n_in,
                              void* d_out, int out_size, void* d_ws, size_t ws_size,
                              hipStream_t stream) {
  const float* h   = (const float*)d_in[0];
  const int*   adj = (const int*)d_in[1];
  const float* W   = (const float*)d_in[2];
  const float* a   = (const float*)d_in[3];
  float* out = (float*)d_out;

  char* ws = (char*)d_ws;
  _Float16* whT = (_Float16*)ws;                          // 64*8192*2 = 1 MiB
  float* wh1 = (float*)(ws + (1 << 20));                  // 32 KiB
  float* wh2 = (float*)(ws + (1 << 20) + 32768);          // 32 KiB
  float* G   = (float*)(ws + (1 << 20) + 65536);          // 4 B

  k1_wh<<<dim3(256), dim3(256), 0, stream>>>(h, W, a, whT, wh1, wh2);
  k1b_max<<<dim3(1), dim3(256), 0, stream>>>(wh2, G);
  k2_attn<<<dim3(512), dim3(256), 0, stream>>>(adj, whT, wh1, wh2, G, out);
}

// Round 3
// 132.803 us; speedup vs baseline: 1.0052x; 1.0052x over previous
//
#include <hip/hip_runtime.h>
#include <cstdint>
#include <cstddef>

#define LRALPHA 0.2f

typedef _Float16 half8 __attribute__((ext_vector_type(8)));
typedef float f32x4 __attribute__((ext_vector_type(4)));

// ---------------------------------------------------------------------------
// Kernel 1: Wh = h @ W  (8192x512 @ 512x64), writes:
//   whT  : f16 [64][8192]   (transposed, feeds MFMA B-fragments directly)
//   wh1  : f32 [8192]       (Wh @ a[:64])
//   wh2  : f32 [8192]       (Wh @ a[64:])
// ---------------------------------------------------------------------------
__global__ __launch_bounds__(256) void k1_wh(
    const float* __restrict__ h, const float* __restrict__ W, const float* __restrict__ a,
    _Float16* __restrict__ whT, float* __restrict__ wh1, float* __restrict__ wh2)
{
  __shared__ __align__(16) float h_lds[32][34];   // [k][row]
  __shared__ __align__(16) float w_lds[32][64];   // [k][col]
  __shared__ __align__(16) _Float16 whT_l[64][32];

  const int t = threadIdx.x;
  const int tx = t & 15, ty = t >> 4;
  const int i0 = blockIdx.x * 32;

  const int hrow = t >> 3, hk4 = (t & 7) * 4;
  const int wk = t >> 3, wc = (t & 7) * 8;

  float acc00 = 0, acc01 = 0, acc02 = 0, acc03 = 0;
  float acc10 = 0, acc11 = 0, acc12 = 0, acc13 = 0;

  float4 hv  = *reinterpret_cast<const float4*>(&h[(size_t)(i0 + hrow) * 512 + hk4]);
  float4 wv0 = *reinterpret_cast<const float4*>(&W[(size_t)wk * 64 + wc]);
  float4 wv1 = *reinterpret_cast<const float4*>(&W[(size_t)wk * 64 + wc + 4]);

  for (int k0 = 0; k0 < 512; k0 += 32) {
    h_lds[hk4 + 0][hrow] = hv.x;
    h_lds[hk4 + 1][hrow] = hv.y;
    h_lds[hk4 + 2][hrow] = hv.z;
    h_lds[hk4 + 3][hrow] = hv.w;
    *reinterpret_cast<float4*>(&w_lds[wk][wc])     = wv0;
    *reinterpret_cast<float4*>(&w_lds[wk][wc + 4]) = wv1;
    __syncthreads();
    if (k0 + 32 < 512) {
      hv  = *reinterpret_cast<const float4*>(&h[(size_t)(i0 + hrow) * 512 + k0 + 32 + hk4]);
      wv0 = *reinterpret_cast<const float4*>(&W[(size_t)(k0 + 32 + wk) * 64 + wc]);
      wv1 = *reinterpret_cast<const float4*>(&W[(size_t)(k0 + 32 + wk) * 64 + wc + 4]);
    }
#pragma unroll
    for (int kk = 0; kk < 32; ++kk) {
      float2 av = *reinterpret_cast<const float2*>(&h_lds[kk][ty * 2]);
      float4 bv = *reinterpret_cast<const float4*>(&w_lds[kk][tx * 4]);
      acc00 += av.x * bv.x; acc01 += av.x * bv.y; acc02 += av.x * bv.z; acc03 += av.x * bv.w;
      acc10 += av.y * bv.x; acc11 += av.y * bv.y; acc12 += av.y * bv.z; acc13 += av.y * bv.w;
    }
    __syncthreads();
  }

  const float a10 = a[tx * 4 + 0], a11 = a[tx * 4 + 1], a12 = a[tx * 4 + 2], a13 = a[tx * 4 + 3];
  const float a20 = a[64 + tx * 4 + 0], a21 = a[64 + tx * 4 + 1], a22 = a[64 + tx * 4 + 2], a23 = a[64 + tx * 4 + 3];
  float s1_0 = acc00 * a10 + acc01 * a11 + acc02 * a12 + acc03 * a13;
  float s1_1 = acc10 * a10 + acc11 * a11 + acc12 * a12 + acc13 * a13;
  float s2_0 = acc00 * a20 + acc01 * a21 + acc02 * a22 + acc03 * a23;
  float s2_1 = acc10 * a20 + acc11 * a21 + acc12 * a22 + acc13 * a23;
#pragma unroll
  for (int m = 1; m < 16; m <<= 1) {
    s1_0 += __shfl_xor(s1_0, m); s1_1 += __shfl_xor(s1_1, m);
    s2_0 += __shfl_xor(s2_0, m); s2_1 += __shfl_xor(s2_1, m);
  }
  if (tx == 0) {
    wh1[i0 + ty * 2 + 0] = s1_0; wh1[i0 + ty * 2 + 1] = s1_1;
    wh2[i0 + ty * 2 + 0] = s2_0; wh2[i0 + ty * 2 + 1] = s2_1;
  }

  whT_l[tx * 4 + 0][ty * 2 + 0] = (_Float16)acc00;
  whT_l[tx * 4 + 1][ty * 2 + 0] = (_Float16)acc01;
  whT_l[tx * 4 + 2][ty * 2 + 0] = (_Float16)acc02;
  whT_l[tx * 4 + 3][ty * 2 + 0] = (_Float16)acc03;
  whT_l[tx * 4 + 0][ty * 2 + 1] = (_Float16)acc10;
  whT_l[tx * 4 + 1][ty * 2 + 1] = (_Float16)acc11;
  whT_l[tx * 4 + 2][ty * 2 + 1] = (_Float16)acc12;
  whT_l[tx * 4 + 3][ty * 2 + 1] = (_Float16)acc13;
  __syncthreads();
  {
    const int c = t >> 2, r8 = (t & 3) * 8;
    half8 v = *reinterpret_cast<const half8*>(&whT_l[c][r8]);
    *reinterpret_cast<half8*>(&whT[(size_t)c * 8192 + i0 + r8]) = v;
  }
}

// ---------------------------------------------------------------------------
// Kernel 1b: G = max(wh2)
// ---------------------------------------------------------------------------
__global__ __launch_bounds__(256) void k1b_max(const float* __restrict__ wh2,
                                               float* __restrict__ G)
{
  const int t = threadIdx.x;
  float m = -1e30f;
  for (int i = t; i < 8192; i += 256) m = fmaxf(m, wh2[i]);
#pragma unroll
  for (int mask = 32; mask >= 1; mask >>= 1) m = fmaxf(m, __shfl_xor(m, mask));
  __shared__ float wm[4];
  if ((t & 63) == 0) wm[t >> 6] = m;
  __syncthreads();
  if (t == 0) G[0] = fmaxf(fmaxf(wm[0], wm[1]), fmaxf(wm[2], wm[3]));
}

// ---------------------------------------------------------------------------
// Kernel 2 (v3): barrier-free masked-softmax + PV, big row tiles.
// Grid: 256 blocks = 64 row-groups (bi) x 4 j-splits (bj); bj = bid%4 so the
// round-robin block->XCD map pins one 512KB whT slice per XCD (L2-resident).
// Block: 512 thr = 8 waves; wave w owns rows [bi*128+w*16, +16) over
// j in [bj*2048, +2048). Lane owns its MFMA A-fragment -> no LDS/barriers.
// whT nominal traffic: 8.6GB / 128 rows = 67MB (vs 512MB in v2).
// Partials (O, denom) per bj-slice -> combined in k3.
// ---------------------------------------------------------------------------
__global__ __launch_bounds__(512) void k2_attn(
    const int* __restrict__ adj, const _Float16* __restrict__ whT,
    const float* __restrict__ wh1, const float* __restrict__ wh2,
    const float* __restrict__ Gp, float* __restrict__ Opart, float* __restrict__ Dpart)
{
  const int t = threadIdx.x;
  const int lane = t & 63;
  const int w = t >> 6;            // wave id 0..7 = row-subtile
  const int c = lane & 15;         // A-row / B-col index
  const int ks = lane >> 4;        // k-subgroup 0..3
  const int bj = blockIdx.x & 3;   // j-split (pins whT slice per XCD)
  const int bi = blockIdx.x >> 2;  // row-group
  const int row0 = bi * 128 + w * 16;

  const float Gv = Gp[0];
  const float w1r = wh1[row0 + c];
  const float mx = w1r + Gv;
  const float mh = fmaxf(mx, LRALPHA * mx);   // >= all scores of this row (lrelu monotone)

  const int*      adjp = adj + (size_t)(row0 + c) * 8192 + bj * 2048 + ks * 8;
  const float*    wh2p = wh2 + bj * 2048 + ks * 8;
  const _Float16* bp0  = whT + (size_t)c * 8192 + bj * 2048 + ks * 8;
  const _Float16* bp1  = bp0 + (size_t)16 * 8192;
  const _Float16* bp2  = bp0 + (size_t)32 * 8192;
  const _Float16* bp3  = bp0 + (size_t)48 * 8192;

  f32x4 acc0 = {0.f,0.f,0.f,0.f}, acc1 = {0.f,0.f,0.f,0.f};
  f32x4 acc2 = {0.f,0.f,0.f,0.f}, acc3 = {0.f,0.f,0.f,0.f};
  float ps = 0.f;

  int4 Aa0, Aa1, Ba0, Ba1;
  float4 Aw0, Aw1, Bw0, Bw1;
  half8 Ab0, Ab1, Ab2, Ab3, Bb0, Bb1, Bb2, Bb3;

#define LOADSET(P, CI) do { const int jj_ = (CI) * 32;                          \
    P##a0 = *reinterpret_cast<const int4*>(adjp + jj_);                         \
    P##a1 = *reinterpret_cast<const int4*>(adjp + jj_ + 4);                     \
    P##w0 = *reinterpret_cast<const float4*>(wh2p + jj_);                       \
    P##w1 = *reinterpret_cast<const float4*>(wh2p + jj_ + 4);                   \
    P##b0 = *reinterpret_cast<const half8*>(bp0 + jj_);                         \
    P##b1 = *reinterpret_cast<const half8*>(bp1 + jj_);                         \
    P##b2 = *reinterpret_cast<const half8*>(bp2 + jj_);                         \
    P##b3 = *reinterpret_cast<const half8*>(bp3 + jj_); } while (0)

#define BODY(P, NEXTCI) do {                                                    \
    const int4 ca0 = P##a0, ca1 = P##a1;                                        \
    const float4 cw0 = P##w0, cw1 = P##w1;                                      \
    const half8 cb0 = P##b0, cb1 = P##b1, cb2 = P##b2, cb3 = P##b3;             \
    if ((NEXTCI) < 64) LOADSET(P, NEXTCI);                                      \
    half8 af;                                                                   \
    { float s_ = w1r + cw0.x; s_ = fmaxf(s_, LRALPHA*s_);                       \
      float p_ = (ca0.x > 0) ? __expf(s_ - mh) : 0.f; ps += p_; af[0] = (_Float16)p_; } \
    { float s_ = w1r + cw0.y; s_ = fmaxf(s_, LRALPHA*s_);                       \
      float p_ = (ca0.y > 0) ? __expf(s_ - mh) : 0.f; ps += p_; af[1] = (_Float16)p_; } \
    { float s_ = w1r + cw0.z; s_ = fmaxf(s_, LRALPHA*s_);                       \
      float p_ = (ca0.z > 0) ? __expf(s_ - mh) : 0.f; ps += p_; af[2] = (_Float16)p_; } \
    { float s_ = w1r + cw0.w; s_ = fmaxf(s_, LRALPHA*s_);                       \
      float p_ = (ca0.w > 0) ? __expf(s_ - mh) : 0.f; ps += p_; af[3] = (_Float16)p_; } \
    { float s_ = w1r + cw1.x; s_ = fmaxf(s_, LRALPHA*s_);                       \
      float p_ = (ca1.x > 0) ? __expf(s_ - mh) : 0.f; ps += p_; af[4] = (_Float16)p_; } \
    { float s_ = w1r + cw1.y; s_ = fmaxf(s_, LRALPHA*s_);                       \
      float p_ = (ca1.y > 0) ? __expf(s_ - mh) : 0.f; ps += p_; af[5] = (_Float16)p_; } \
    { float s_ = w1r + cw1.z; s_ = fmaxf(s_, LRALPHA*s_);                       \
      float p_ = (ca1.z > 0) ? __expf(s_ - mh) : 0.f; ps += p_; af[6] = (_Float16)p_; } \
    { float s_ = w1r + cw1.w; s_ = fmaxf(s_, LRALPHA*s_);                       \
      float p_ = (ca1.w > 0) ? __expf(s_ - mh) : 0.f; ps += p_; af[7] = (_Float16)p_; } \
    acc0 = __builtin_amdgcn_mfma_f32_16x16x32_f16(af, cb0, acc0, 0, 0, 0);      \
    acc1 = __builtin_amdgcn_mfma_f32_16x16x32_f16(af, cb1, acc1, 0, 0, 0);      \
    acc2 = __builtin_amdgcn_mfma_f32_16x16x32_f16(af, cb2, acc2, 0, 0, 0);      \
    acc3 = __builtin_amdgcn_mfma_f32_16x16x32_f16(af, cb3, acc3, 0, 0, 0);      \
  } while (0)

  LOADSET(A, 0);
  LOADSET(B, 1);

  for (int ci = 0; ci < 64; ci += 2) {
    BODY(A, ci + 2);
    BODY(B, ci + 3);
  }
#undef BODY
#undef LOADSET

  // per-row denom partial: reduce across the 4 k-subgroups
  float r = ps;
  r += __shfl_xor(r, 16);
  r += __shfl_xor(r, 32);
  if (ks == 0) Dpart[(size_t)bj * 8192 + row0 + c] = r;

  // write O partial: 16 rows x 64 cols f32 per wave
  float* ob = Opart + ((size_t)bj * 8192 + row0 + ks * 4) * 64;
#pragma unroll
  for (int q = 0; q < 4; ++q) {
    ob[(size_t)q * 64 +  0 + c] = acc0[q];
    ob[(size_t)q * 64 + 16 + c] = acc1[q];
    ob[(size_t)q * 64 + 32 + c] = acc2[q];
    ob[(size_t)q * 64 + 48 + c] = acc3[q];
  }
}

// ---------------------------------------------------------------------------
// Kernel 3: combine j-split partials: out = elu( (sum_bj O) / (sum_bj D) )
// ---------------------------------------------------------------------------
__global__ __launch_bounds__(256) void k3_combine(
    const float* __restrict__ Opart, const float* __restrict__ Dpart,
    float* __restrict__ out)
{
  const int idx = blockIdx.x * 256 + threadIdx.x;   // 131072 = 8192 rows x 16 quads
  const int row = idx >> 4, c4 = (idx & 15) * 4;

  const float d = Dpart[row] + Dpart[8192 + row] + Dpart[2 * 8192 + row] + Dpart[3 * 8192 + row];
  const float inv = 1.0f / d;

  const size_t o = (size_t)row * 64 + c4;
  float4 v0 = *reinterpret_cast<const float4*>(&Opart[o]);
  float4 v1 = *reinterpret_cast<const float4*>(&Opart[(size_t)8192 * 64 + o]);
  float4 v2 = *reinterpret_cast<const float4*>(&Opart[(size_t)2 * 8192 * 64 + o]);
  float4 v3 = *reinterpret_cast<const float4*>(&Opart[(size_t)3 * 8192 * 64 + o]);

  float4 r;
  r.x = (v0.x + v1.x + v2.x + v3.x) * inv;
  r.y = (v0.y + v1.y + v2.y + v3.y) * inv;
  r.z = (v0.z + v1.z + v2.z + v3.z) * inv;
  r.w = (v0.w + v1.w + v2.w + v3.w) * inv;
  r.x = r.x > 0.f ? r.x : __expf(r.x) - 1.f;
  r.y = r.y > 0.f ? r.y : __expf(r.y) - 1.f;
  r.z = r.z > 0.f ? r.z : __expf(r.z) - 1.f;
  r.w = r.w > 0.f ? r.w : __expf(r.w) - 1.f;
  *reinterpret_cast<float4*>(&out[o]) = r;
}

// ---------------------------------------------------------------------------
extern "C" void kernel_launch(void* const* d_in, const int* in_sizes, int n_in,
                              void* d_out, int out_size, void* d_ws, size_t ws_size,
                              hipStream_t stream) {
  const float* h   = (const float*)d_in[0];
  const int*   adj = (const int*)d_in[1];
  const float* W   = (const float*)d_in[2];
  const float* a   = (const float*)d_in[3];
  float* out = (float*)d_out;

  char* ws = (char*)d_ws;
  _Float16* whT = (_Float16*)ws;                           // [0, 1MB)
  float* wh1  = (float*)(ws + 0x100000);                   // 32 KB
  float* wh2  = (float*)(ws + 0x108000);                   // 32 KB
  float* G    = (float*)(ws + 0x110000);                   // 4 B
  float* Dpart = (float*)(ws + 0x110100);                  // 4*8192*4 = 128 KB
  float* Opart = (float*)(ws + 0x140000);                  // 4*8192*64*4 = 8 MB

  k1_wh<<<dim3(256), dim3(256), 0, stream>>>(h, W, a, whT, wh1, wh2);
  k1b_max<<<dim3(1), dim3(256), 0, stream>>>(wh2, G);
  k2_attn<<<dim3(256), dim3(512), 0, stream>>>(adj, whT, wh1, wh2, G, Opart, Dpart);
  k3_combine<<<dim3(512), dim3(256), 0, stream>>>(Opart, Dpart, out);
}

// Round 4
// 123.284 us; speedup vs baseline: 1.0829x; 1.0772x over previous
//
#include <hip/hip_runtime.h>
#include <cstdint>
#include <cstddef>

#define LRALPHA 0.2f

typedef _Float16 half8 __attribute__((ext_vector_type(8)));
typedef float f32x4 __attribute__((ext_vector_type(4)));

// ---------------------------------------------------------------------------
// Kernel 0: bitpack adj (256MB int32) -> bits8 (8MB, bit e of byte b =
// adj[b*8+e] > 0). Pure sequential stream at max occupancy -> ~7 TB/s.
// ---------------------------------------------------------------------------
__global__ __launch_bounds__(256) void k0_bitpack(const int* __restrict__ adj,
                                                  unsigned char* __restrict__ bits8)
{
  const int nb = 8192 * 1024;              // total bytes of mask
  const int stride = gridDim.x * 256;
  for (int b = blockIdx.x * 256 + threadIdx.x; b < nb; b += stride) {
    const int4* p = reinterpret_cast<const int4*>(adj + (size_t)b * 8);
    const int4 x = p[0], y = p[1];
    unsigned m = (x.x > 0 ? 1u : 0u) | (x.y > 0 ? 2u : 0u)
               | (x.z > 0 ? 4u : 0u) | (x.w > 0 ? 8u : 0u)
               | (y.x > 0 ? 16u : 0u) | (y.y > 0 ? 32u : 0u)
               | (y.z > 0 ? 64u : 0u) | (y.w > 0 ? 128u : 0u);
    bits8[b] = (unsigned char)m;
  }
}

// ---------------------------------------------------------------------------
// Kernel 1: Wh = h @ W (8192x512 @ 512x64), writes:
//   whTsw : f16, swizzled MFMA-B layout: [j/32][cp:4][c:16][ks:4][e:8]
//           element = Wh[j32*32 + ks*8 + e][cp*16 + c]   (1 MiB total)
//   wh1/wh2 : f32 [8192] row/col score terms
// ---------------------------------------------------------------------------
__global__ __launch_bounds__(256) void k1_wh(
    const float* __restrict__ h, const float* __restrict__ W, const float* __restrict__ a,
    _Float16* __restrict__ whTsw, float* __restrict__ wh1, float* __restrict__ wh2)
{
  __shared__ __align__(16) float h_lds[32][34];   // [k][row]
  __shared__ __align__(16) float w_lds[32][64];   // [k][col]
  __shared__ __align__(16) _Float16 whT_l[64][32]; // [col][ilocal]

  const int t = threadIdx.x;
  const int tx = t & 15, ty = t >> 4;
  const int i0 = blockIdx.x * 32;

  const int hrow = t >> 3, hk4 = (t & 7) * 4;
  const int wk = t >> 3, wc = (t & 7) * 8;

  float acc00 = 0, acc01 = 0, acc02 = 0, acc03 = 0;
  float acc10 = 0, acc11 = 0, acc12 = 0, acc13 = 0;

  float4 hv  = *reinterpret_cast<const float4*>(&h[(size_t)(i0 + hrow) * 512 + hk4]);
  float4 wv0 = *reinterpret_cast<const float4*>(&W[(size_t)wk * 64 + wc]);
  float4 wv1 = *reinterpret_cast<const float4*>(&W[(size_t)wk * 64 + wc + 4]);

  for (int k0 = 0; k0 < 512; k0 += 32) {
    h_lds[hk4 + 0][hrow] = hv.x;
    h_lds[hk4 + 1][hrow] = hv.y;
    h_lds[hk4 + 2][hrow] = hv.z;
    h_lds[hk4 + 3][hrow] = hv.w;
    *reinterpret_cast<float4*>(&w_lds[wk][wc])     = wv0;
    *reinterpret_cast<float4*>(&w_lds[wk][wc + 4]) = wv1;
    __syncthreads();
    if (k0 + 32 < 512) {
      hv  = *reinterpret_cast<const float4*>(&h[(size_t)(i0 + hrow) * 512 + k0 + 32 + hk4]);
      wv0 = *reinterpret_cast<const float4*>(&W[(size_t)(k0 + 32 + wk) * 64 + wc]);
      wv1 = *reinterpret_cast<const float4*>(&W[(size_t)(k0 + 32 + wk) * 64 + wc + 4]);
    }
#pragma unroll
    for (int kk = 0; kk < 32; ++kk) {
      float2 av = *reinterpret_cast<const float2*>(&h_lds[kk][ty * 2]);
      float4 bv = *reinterpret_cast<const float4*>(&w_lds[kk][tx * 4]);
      acc00 += av.x * bv.x; acc01 += av.x * bv.y; acc02 += av.x * bv.z; acc03 += av.x * bv.w;
      acc10 += av.y * bv.x; acc11 += av.y * bv.y; acc12 += av.y * bv.z; acc13 += av.y * bv.w;
    }
    __syncthreads();
  }

  const float a10 = a[tx * 4 + 0], a11 = a[tx * 4 + 1], a12 = a[tx * 4 + 2], a13 = a[tx * 4 + 3];
  const float a20 = a[64 + tx * 4 + 0], a21 = a[64 + tx * 4 + 1], a22 = a[64 + tx * 4 + 2], a23 = a[64 + tx * 4 + 3];
  float s1_0 = acc00 * a10 + acc01 * a11 + acc02 * a12 + acc03 * a13;
  float s1_1 = acc10 * a10 + acc11 * a11 + acc12 * a12 + acc13 * a13;
  float s2_0 = acc00 * a20 + acc01 * a21 + acc02 * a22 + acc03 * a23;
  float s2_1 = acc10 * a20 + acc11 * a21 + acc12 * a22 + acc13 * a23;
#pragma unroll
  for (int m = 1; m < 16; m <<= 1) {
    s1_0 += __shfl_xor(s1_0, m); s1_1 += __shfl_xor(s1_1, m);
    s2_0 += __shfl_xor(s2_0, m); s2_1 += __shfl_xor(s2_1, m);
  }
  if (tx == 0) {
    wh1[i0 + ty * 2 + 0] = s1_0; wh1[i0 + ty * 2 + 1] = s1_1;
    wh2[i0 + ty * 2 + 0] = s2_0; wh2[i0 + ty * 2 + 1] = s2_1;
  }

  whT_l[tx * 4 + 0][ty * 2 + 0] = (_Float16)acc00;
  whT_l[tx * 4 + 1][ty * 2 + 0] = (_Float16)acc01;
  whT_l[tx * 4 + 2][ty * 2 + 0] = (_Float16)acc02;
  whT_l[tx * 4 + 3][ty * 2 + 0] = (_Float16)acc03;
  whT_l[tx * 4 + 0][ty * 2 + 1] = (_Float16)acc10;
  whT_l[tx * 4 + 1][ty * 2 + 1] = (_Float16)acc11;
  whT_l[tx * 4 + 2][ty * 2 + 1] = (_Float16)acc12;
  whT_l[tx * 4 + 3][ty * 2 + 1] = (_Float16)acc13;
  __syncthreads();
  {
    // swizzled store: this block IS whTsw j-block (i0>>5). thread t -> (cp,cc,ks)
    const int cp = t >> 6, cc = (t >> 2) & 15, ks = t & 3;
    half8 v = *reinterpret_cast<const half8*>(&whT_l[cp * 16 + cc][ks * 8]);
    *reinterpret_cast<half8*>(&whTsw[(size_t)(i0 >> 5) * 2048 + cp * 512 + (cc * 4 + ks) * 8]) = v;
  }
}

// ---------------------------------------------------------------------------
// Kernel 1b: G = max(wh2)
// ---------------------------------------------------------------------------
__global__ __launch_bounds__(256) void k1b_max(const float* __restrict__ wh2,
                                               float* __restrict__ G)
{
  const int t = threadIdx.x;
  float m = -1e30f;
  for (int i = t; i < 8192; i += 256) m = fmaxf(m, wh2[i]);
#pragma unroll
  for (int mask = 32; mask >= 1; mask >>= 1) m = fmaxf(m, __shfl_xor(m, mask));
  __shared__ float wm[4];
  if ((t & 63) == 0) wm[t >> 6] = m;
  __syncthreads();
  if (t == 0) G[0] = fmaxf(fmaxf(wm[0], wm[1]), fmaxf(wm[2], wm[3]));
}

// ---------------------------------------------------------------------------
// Kernel 2 (v4): all-cache masked-softmax + PV.
// 512 blocks x 512 thr. Block = 16 rows, full j; wave w owns j in [w*1024,
// +1024) (split-K x8, combined in LDS, single barrier). Reads: bits8 (16KB/
// block), wh2 (32KB), whTsw (1MB, L2-resident; each B-frag load = dense 1KB
// region). Lane owns its MFMA A-fragment: c=lane&15 (row), ks=lane>>4.
// ---------------------------------------------------------------------------
__global__ __launch_bounds__(512) void k2_attn(
    const unsigned char* __restrict__ bits8, const _Float16* __restrict__ whTsw,
    const float* __restrict__ wh1, const float* __restrict__ wh2,
    const float* __restrict__ Gp, float* __restrict__ out)
{
  __shared__ __align__(16) float Osm[8][16][64];  // 32 KB split-K partials
  __shared__ float Dsm[8][16];

  const int t = threadIdx.x;
  const int lane = t & 63;
  const int w = t >> 6;            // wave id = K-slice
  const int c = lane & 15;         // A-row / B-col index
  const int ks = lane >> 4;        // k-subgroup 0..3
  const int i0 = blockIdx.x * 16;

  const float Gv = Gp[0];
  const float w1r = wh1[i0 + c];
  const float mx = w1r + Gv;
  const float mh = fmaxf(mx, LRALPHA * mx);   // >= all scores of this row

  const unsigned char* mp = bits8 + (size_t)(i0 + c) * 1024 + w * 128 + ks;
  const float* wh2p = wh2 + w * 1024 + ks * 8;
  const _Float16* bp = whTsw + (size_t)(w * 32) * 2048 + (c * 4 + ks) * 8;

  f32x4 acc0 = {0.f,0.f,0.f,0.f}, acc1 = {0.f,0.f,0.f,0.f};
  f32x4 acc2 = {0.f,0.f,0.f,0.f}, acc3 = {0.f,0.f,0.f,0.f};
  float ps = 0.f;

  unsigned Am, Bm;
  float4 Aw0, Aw1, Bw0, Bw1;
  half8 Ab0, Ab1, Ab2, Ab3, Bb0, Bb1, Bb2, Bb3;

#define LOADSET(P, CI) do {                                                     \
    P##m  = mp[(CI) * 4];                                                       \
    P##w0 = *reinterpret_cast<const float4*>(wh2p + (CI) * 32);                 \
    P##w1 = *reinterpret_cast<const float4*>(wh2p + (CI) * 32 + 4);             \
    P##b0 = *reinterpret_cast<const half8*>(bp + (size_t)(CI) * 2048);          \
    P##b1 = *reinterpret_cast<const half8*>(bp + (size_t)(CI) * 2048 + 512);    \
    P##b2 = *reinterpret_cast<const half8*>(bp + (size_t)(CI) * 2048 + 1024);   \
    P##b3 = *reinterpret_cast<const half8*>(bp + (size_t)(CI) * 2048 + 1536); } while (0)

#define BODY(P, NEXTCI) do {                                                    \
    const unsigned cm = P##m;                                                   \
    const float4 cw0 = P##w0, cw1 = P##w1;                                      \
    const half8 cb0 = P##b0, cb1 = P##b1, cb2 = P##b2, cb3 = P##b3;             \
    if ((NEXTCI) < 32) LOADSET(P, NEXTCI);                                      \
    half8 af;                                                                   \
    { float s_ = w1r + cw0.x; s_ = fmaxf(s_, LRALPHA*s_);                       \
      float p_ = (cm & 1u)   ? __expf(s_ - mh) : 0.f; ps += p_; af[0] = (_Float16)p_; } \
    { float s_ = w1r + cw0.y; s_ = fmaxf(s_, LRALPHA*s_);                       \
      float p_ = (cm & 2u)   ? __expf(s_ - mh) : 0.f; ps += p_; af[1] = (_Float16)p_; } \
    { float s_ = w1r + cw0.z; s_ = fmaxf(s_, LRALPHA*s_);                       \
      float p_ = (cm & 4u)   ? __expf(s_ - mh) : 0.f; ps += p_; af[2] = (_Float16)p_; } \
    { float s_ = w1r + cw0.w; s_ = fmaxf(s_, LRALPHA*s_);                       \
      float p_ = (cm & 8u)   ? __expf(s_ - mh) : 0.f; ps += p_; af[3] = (_Float16)p_; } \
    { float s_ = w1r + cw1.x; s_ = fmaxf(s_, LRALPHA*s_);                       \
      float p_ = (cm & 16u)  ? __expf(s_ - mh) : 0.f; ps += p_; af[4] = (_Float16)p_; } \
    { float s_ = w1r + cw1.y; s_ = fmaxf(s_, LRALPHA*s_);                       \
      float p_ = (cm & 32u)  ? __expf(s_ - mh) : 0.f; ps += p_; af[5] = (_Float16)p_; } \
    { float s_ = w1r + cw1.z; s_ = fmaxf(s_, LRALPHA*s_);                       \
      float p_ = (cm & 64u)  ? __expf(s_ - mh) : 0.f; ps += p_; af[6] = (_Float16)p_; } \
    { float s_ = w1r + cw1.w; s_ = fmaxf(s_, LRALPHA*s_);                       \
      float p_ = (cm & 128u) ? __expf(s_ - mh) : 0.f; ps += p_; af[7] = (_Float16)p_; } \
    acc0 = __builtin_amdgcn_mfma_f32_16x16x32_f16(af, cb0, acc0, 0, 0, 0);      \
    acc1 = __builtin_amdgcn_mfma_f32_16x16x32_f16(af, cb1, acc1, 0, 0, 0);      \
    acc2 = __builtin_amdgcn_mfma_f32_16x16x32_f16(af, cb2, acc2, 0, 0, 0);      \
    acc3 = __builtin_amdgcn_mfma_f32_16x16x32_f16(af, cb3, acc3, 0, 0, 0);      \
  } while (0)

  LOADSET(A, 0);
  LOADSET(B, 1);

  for (int ci = 0; ci < 32; ci += 2) {
    BODY(A, ci + 2);
    BODY(B, ci + 3);
  }
#undef BODY
#undef LOADSET

  // per-row denom partial across the 4 k-subgroups
  float r = ps;
  r += __shfl_xor(r, 16);
  r += __shfl_xor(r, 32);
  if (ks == 0) Dsm[w][c] = r;

#pragma unroll
  for (int q = 0; q < 4; ++q) {
    Osm[w][ks * 4 + q][ 0 + c] = acc0[q];
    Osm[w][ks * 4 + q][16 + c] = acc1[q];
    Osm[w][ks * 4 + q][32 + c] = acc2[q];
    Osm[w][ks * 4 + q][48 + c] = acc3[q];
  }
  __syncthreads();

  {
    const int row = t >> 5, c2 = (t & 31) * 2;
    float d = 0.f, sx = 0.f, sy = 0.f;
#pragma unroll
    for (int ww = 0; ww < 8; ++ww) {
      d  += Dsm[ww][row];
      float2 v = *reinterpret_cast<const float2*>(&Osm[ww][row][c2]);
      sx += v.x; sy += v.y;
    }
    const float inv = 1.0f / d;
    float ox = sx * inv, oy = sy * inv;
    ox = ox > 0.f ? ox : __expf(ox) - 1.f;
    oy = oy > 0.f ? oy : __expf(oy) - 1.f;
    float2 o = {ox, oy};
    *reinterpret_cast<float2*>(&out[(size_t)(i0 + row) * 64 + c2]) = o;
  }
}

// ---------------------------------------------------------------------------
extern "C" void kernel_launch(void* const* d_in, const int* in_sizes, int n_in,
                              void* d_out, int out_size, void* d_ws, size_t ws_size,
                              hipStream_t stream) {
  const float* h   = (const float*)d_in[0];
  const int*   adj = (const int*)d_in[1];
  const float* W   = (const float*)d_in[2];
  const float* a   = (const float*)d_in[3];
  float* out = (float*)d_out;

  char* ws = (char*)d_ws;
  _Float16* whTsw = (_Float16*)ws;                         // [0, 1MB)
  float* wh1 = (float*)(ws + 0x100000);                    // 32 KB
  float* wh2 = (float*)(ws + 0x108000);                    // 32 KB
  float* G   = (float*)(ws + 0x110000);                    // 4 B
  unsigned char* bits8 = (unsigned char*)(ws + 0x120000);  // 8 MB

  k0_bitpack<<<dim3(2048), dim3(256), 0, stream>>>(adj, bits8);
  k1_wh<<<dim3(256), dim3(256), 0, stream>>>(h, W, a, whTsw, wh1, wh2);
  k1b_max<<<dim3(1), dim3(256), 0, stream>>>(wh2, G);
  k2_attn<<<dim3(512), dim3(512), 0, stream>>>(bits8, whTsw, wh1, wh2, G, out);
}